// Round 1
// baseline (247.331 us; speedup 1.0000x reference)
//
#include <hip/hip_runtime.h>
#include <stdint.h>

// ================= config =================
#define JAX_PARTITIONABLE 1   // JAX >= 0.4.30 default threefry mode; flip to 0 if absmax ~2-5
#define MFMA_USE_SHORT 0      // flip to 1 if builtin signature wants short8 instead of __bf16 x8

#define NS 10
#define DIM 512
#define NQ 4096
#define NP 1024

typedef unsigned short ushort_t;
#if MFMA_USE_SHORT
typedef short bf16el_t;
#else
typedef __bf16 bf16el_t;
#endif
typedef bf16el_t bf16x8 __attribute__((ext_vector_type(8)));
typedef float floatx4 __attribute__((ext_vector_type(4)));

// ================= threefry2x32-20 (JAX-compatible) =================
__host__ __device__ __forceinline__ uint32_t rotl32(uint32_t x, int r) {
  return (x << r) | (x >> (32 - r));
}

__host__ __device__ __forceinline__ void threefry2x32(uint32_t k0, uint32_t k1,
                                                      uint32_t x0, uint32_t x1,
                                                      uint32_t* o0, uint32_t* o1) {
  uint32_t ks2 = k0 ^ k1 ^ 0x1BD11BDAu;
  x0 += k0; x1 += k1;
#define TF_R(r) { x0 += x1; x1 = rotl32(x1, r); x1 ^= x0; }
  TF_R(13) TF_R(15) TF_R(26) TF_R(6)   x0 += k1;  x1 += ks2 + 1u;
  TF_R(17) TF_R(29) TF_R(16) TF_R(24)  x0 += ks2; x1 += k0 + 2u;
  TF_R(13) TF_R(15) TF_R(26) TF_R(6)   x0 += k0;  x1 += k1 + 3u;
  TF_R(17) TF_R(29) TF_R(16) TF_R(24)  x0 += k1;  x1 += ks2 + 4u;
  TF_R(13) TF_R(15) TF_R(26) TF_R(6)   x0 += ks2; x1 += k0 + 5u;
#undef TF_R
  *o0 = x0; *o1 = x1;
}

// random_bits(key, 32, n)[idx]
__device__ __forceinline__ uint32_t jax_random_bits(uint32_t k0, uint32_t k1,
                                                    uint32_t idx, uint32_t half) {
  uint32_t o0, o1;
#if JAX_PARTITIONABLE
  threefry2x32(k0, k1, 0u, idx, &o0, &o1);
  return o0 ^ o1;               // bit_width<=32 path: bits1 ^ bits2, counter = linear index
#else
  if (idx < half) { threefry2x32(k0, k1, idx, half + idx, &o0, &o1); return o0; }
  threefry2x32(k0, k1, idx - half, idx, &o0, &o1);
  return o1;
#endif
}

// XLA ErfInv32 (Giles single-precision polynomial)
__device__ __forceinline__ float erfinvf_xla(float x) {
  float w = -log1pf(-x * x);
  float p;
  if (w < 5.0f) {
    w -= 2.5f;
    p = 2.81022636e-08f;
    p = fmaf(p, w, 3.43273939e-07f);
    p = fmaf(p, w, -3.5233877e-06f);
    p = fmaf(p, w, -4.39150654e-06f);
    p = fmaf(p, w, 0.00021858087f);
    p = fmaf(p, w, -0.00125372503f);
    p = fmaf(p, w, -0.00417768164f);
    p = fmaf(p, w, 0.246640727f);
    p = fmaf(p, w, 1.50140941f);
  } else {
    w = sqrtf(w) - 3.0f;
    p = -0.000200214257f;
    p = fmaf(p, w, 0.000100950558f);
    p = fmaf(p, w, 0.00134934322f);
    p = fmaf(p, w, -0.00367342844f);
    p = fmaf(p, w, 0.00573950773f);
    p = fmaf(p, w, -0.0076224613f);
    p = fmaf(p, w, 0.00943887047f);
    p = fmaf(p, w, 1.00167406f);
    p = fmaf(p, w, 2.83297682f);
  }
  return p * x;
}

// jax.random.normal: uniform in (lo,1) with lo=nextafter(-1,0), then sqrt(2)*erfinv
__device__ __forceinline__ float jax_bits_to_normal(uint32_t bits) {
  float f = __uint_as_float((bits >> 9) | 0x3F800000u) - 1.0f;  // [0,1)
  float u = f * 2.0f - 0.99999994f;   // (maxval-minval) rounds to exactly 2.0f
  u = fmaxf(u, -0.99999994f);
  return 1.41421356f * erfinvf_xla(u);
}

__device__ __forceinline__ float softplusf(float x) { return log1pf(expf(x)); }

__device__ __forceinline__ float bf2f(ushort_t u) {
  return __uint_as_float(((uint32_t)u) << 16);
}
__device__ __forceinline__ ushort_t f2bf(float f) {  // round-to-nearest-even
  uint32_t u = __float_as_uint(f);
  u += 0x7FFFu + ((u >> 16) & 1u);
  return (ushort_t)(u >> 16);
}

// ================= kernels =================

// W samples, stored TRANSPOSED: wt[s][e][k] = bf16( mu[k][e] + softplus(rho[k][e]) * eps_w[s][k][e] )
__global__ __launch_bounds__(256) void gen_w_kernel(const float* __restrict__ wmu,
                                                    const float* __restrict__ wrho,
                                                    ushort_t* __restrict__ wt,
                                                    uint32_t kw0, uint32_t kw1) {
  uint32_t tid = blockIdx.x * 256u + threadIdx.x;   // 2,621,440 exactly
  uint32_t s = tid >> 18;
  uint32_t r = tid & 0x3FFFFu;
  uint32_t e = r >> 9;
  uint32_t k = r & 511u;
  uint32_t eps_idx = (s << 18) | (k << 9) | e;      // JAX order [s][k][e]
  uint32_t bits = jax_random_bits(kw0, kw1, eps_idx, (NS * DIM * DIM) / 2);
  float n = jax_bits_to_normal(bits);
  uint32_t mi = (k << 9) | e;
  float w = wmu[mi] + softplusf(wrho[mi]) * n;
  wt[tid] = f2bf(w);
}

// b[s][e] = bias_mu[e] + softplus(bias_rho[e]) * eps_b[s][e]   (fp32)
__global__ __launch_bounds__(256) void gen_b_kernel(const float* __restrict__ bmu,
                                                    const float* __restrict__ brho,
                                                    float* __restrict__ bvec,
                                                    uint32_t kb0, uint32_t kb1) {
  uint32_t tid = blockIdx.x * 256u + threadIdx.x;   // 5120 exactly
  uint32_t e = tid & 511u;
  uint32_t bits = jax_random_bits(kb0, kb1, tid, (NS * DIM) / 2);
  float n = jax_bits_to_normal(bits);
  bvec[tid] = bmu[e] + softplusf(brho[e]) * n;
}

__global__ __launch_bounds__(256) void cvt_q_kernel(const float* __restrict__ qf,
                                                    ushort_t* __restrict__ qb) {
  int i = (blockIdx.x * 256 + threadIdx.x) * 4;     // 2,097,152 elems exactly
  float4 v = *(const float4*)&qf[i];
  uint2 r;
  r.x = (uint32_t)f2bf(v.x) | ((uint32_t)f2bf(v.y) << 16);
  r.y = (uint32_t)f2bf(v.z) | ((uint32_t)f2bf(v.w) << 16);
  *(uint2*)&qb[i] = r;
}

// prototypes -> bf16 + sq_p from the bf16-rounded values (keeps dist == ||tq~ - p~||)
__global__ __launch_bounds__(64) void cvt_p_sqp_kernel(const float* __restrict__ pf,
                                                       ushort_t* __restrict__ pb,
                                                       float* __restrict__ sqp) {
  int p = blockIdx.x;
  int lane = threadIdx.x;
  const float* src = pf + p * DIM + lane * 8;
  float4 a = *(const float4*)src;
  float4 b = *(const float4*)(src + 4);
  float vals[8] = {a.x, a.y, a.z, a.w, b.x, b.y, b.z, b.w};
  ushort_t o[8];
  float ss = 0.f;
#pragma unroll
  for (int i = 0; i < 8; ++i) {
    o[i] = f2bf(vals[i]);
    float f = bf2f(o[i]);
    ss += f * f;
  }
  *(uint4*)&pb[p * DIM + lane * 8] = *(const uint4*)o;
#pragma unroll
  for (int off = 32; off; off >>= 1) ss += __shfl_xor(ss, off, 64);
  if (lane == 0) sqp[p] = ss;
}

// GEMM1: tq[s] = q @ W_s + b_s  (M=4096,N=512,K=512 per s).  64x64 tile, 4 waves of 32x32.
__global__ __launch_bounds__(256) void gemm_tq_kernel(const ushort_t* __restrict__ qb,
                                                      const ushort_t* __restrict__ wt,
                                                      const float* __restrict__ bvec,
                                                      ushort_t* __restrict__ tq) {
  __shared__ __align__(16) ushort_t lsA[64][72];
  __shared__ __align__(16) ushort_t lsB[64][72];
  const int lane = threadIdx.x & 63;
  const int wave = threadIdx.x >> 6;
  const int wm = wave >> 1, wn = wave & 1;
  const int qBase = blockIdx.x * 64;
  const int eBase = blockIdx.y * 64;
  const int s = blockIdx.z;
  const ushort_t* wbase = wt + s * (DIM * DIM);     // layout [e][k]
  const int row = threadIdx.x >> 3;                 // 0..31
  const int c8 = (threadIdx.x & 7) * 8;
  const int cn = lane & 15;
  const int kq = (lane >> 4) * 8;
  const floatx4 fzero = {0.f, 0.f, 0.f, 0.f};
  floatx4 acc[2][2] = {{fzero, fzero}, {fzero, fzero}};
  for (int kt = 0; kt < 8; ++kt) {
    const int k0 = kt * 64;
    __syncthreads();
    *(uint4*)&lsA[row][c8]      = *(const uint4*)&qb[(qBase + row) * DIM + k0 + c8];
    *(uint4*)&lsA[row + 32][c8] = *(const uint4*)&qb[(qBase + row + 32) * DIM + k0 + c8];
    *(uint4*)&lsB[row][c8]      = *(const uint4*)&wbase[(eBase + row) * DIM + k0 + c8];
    *(uint4*)&lsB[row + 32][c8] = *(const uint4*)&wbase[(eBase + row + 32) * DIM + k0 + c8];
    __syncthreads();
#pragma unroll
    for (int kk = 0; kk < 64; kk += 32) {
      bf16x8 aF[2], bF[2];
#pragma unroll
      for (int mi = 0; mi < 2; ++mi)
        aF[mi] = *(const bf16x8*)&lsA[wm * 32 + mi * 16 + cn][kk + kq];
#pragma unroll
      for (int ni = 0; ni < 2; ++ni)
        bF[ni] = *(const bf16x8*)&lsB[wn * 32 + ni * 16 + cn][kk + kq];
#pragma unroll
      for (int mi = 0; mi < 2; ++mi)
#pragma unroll
        for (int ni = 0; ni < 2; ++ni)
          acc[mi][ni] = __builtin_amdgcn_mfma_f32_16x16x32_bf16(aF[mi], bF[ni], acc[mi][ni], 0, 0, 0);
    }
  }
  const int rq = (lane >> 4) * 4;
#pragma unroll
  for (int mi = 0; mi < 2; ++mi)
#pragma unroll
    for (int ni = 0; ni < 2; ++ni) {
      const int e = eBase + wn * 32 + ni * 16 + cn;
      const float bv = bvec[s * DIM + e];
#pragma unroll
      for (int r = 0; r < 4; ++r) {
        const int q = qBase + wm * 32 + mi * 16 + rq + r;
        tq[(size_t)s * (NQ * DIM) + q * DIM + e] = f2bf(acc[mi][ni][r] + bv);
      }
    }
}

// sq_q[s][q] = sum_e tq~^2  (from the stored bf16 values, one wave per row)
__global__ __launch_bounds__(64) void sqq_kernel(const ushort_t* __restrict__ tq,
                                                 float* __restrict__ sqq) {
  int sq = blockIdx.x;
  int lane = threadIdx.x;
  const ushort_t* rowp = tq + (size_t)sq * DIM;
  uint4 v = *(const uint4*)(rowp + lane * 8);
  uint32_t wsv[4] = {v.x, v.y, v.z, v.w};
  float ss = 0.f;
#pragma unroll
  for (int i = 0; i < 4; ++i) {
    float lo = bf2f((ushort_t)(wsv[i] & 0xFFFFu));
    float hi = bf2f((ushort_t)(wsv[i] >> 16));
    ss += lo * lo + hi * hi;
  }
#pragma unroll
  for (int off = 32; off; off >>= 1) ss += __shfl_xor(ss, off, 64);
  if (lane == 0) sqq[sq] = ss;
}

// GEMM2 fused: cross = tq[s] @ P^T, dist = sqrt(max(sq_q+sq_p-2c,1e-12)), accumulate
// sum/sumsq over s, write mean + std(ddof=1).  Tile 64q x 128p, 4 waves of 32q x 64p.
__global__ __launch_bounds__(256) void gemm_dist_kernel(const ushort_t* __restrict__ tq,
                                                        const ushort_t* __restrict__ pb,
                                                        const float* __restrict__ sqq,
                                                        const float* __restrict__ sqp,
                                                        float* __restrict__ out) {
  __shared__ __align__(16) ushort_t lsA[64][72];
  __shared__ __align__(16) ushort_t lsB[128][72];
  const int lane = threadIdx.x & 63;
  const int wave = threadIdx.x >> 6;
  const int wm = wave >> 1;            // q offset 32*wm
  const int wn = wave & 1;             // p offset 64*wn
  const int qBase = blockIdx.x * 64;
  const int pBase = blockIdx.y * 128;
  const int row = threadIdx.x >> 3;
  const int c8 = (threadIdx.x & 7) * 8;
  const int cn = lane & 15;
  const int kq = (lane >> 4) * 8;
  const floatx4 fzero = {0.f, 0.f, 0.f, 0.f};

  float sum[2][4][4] = {};
  float ssq[2][4][4] = {};
  float sqp_v[4];
#pragma unroll
  for (int ni = 0; ni < 4; ++ni) sqp_v[ni] = sqp[pBase + wn * 64 + ni * 16 + cn];

  for (int s = 0; s < NS; ++s) {
    const ushort_t* tqs = tq + (size_t)s * (NQ * DIM);
    floatx4 acc[2][4];
#pragma unroll
    for (int mi = 0; mi < 2; ++mi)
#pragma unroll
      for (int ni = 0; ni < 4; ++ni) acc[mi][ni] = fzero;

    for (int kt = 0; kt < 8; ++kt) {
      const int e0 = kt * 64;
      __syncthreads();
      *(uint4*)&lsA[row][c8]      = *(const uint4*)&tqs[(qBase + row) * DIM + e0 + c8];
      *(uint4*)&lsA[row + 32][c8] = *(const uint4*)&tqs[(qBase + row + 32) * DIM + e0 + c8];
#pragma unroll
      for (int rr = 0; rr < 4; ++rr)
        *(uint4*)&lsB[row + rr * 32][c8] =
            *(const uint4*)&pb[(pBase + row + rr * 32) * DIM + e0 + c8];
      __syncthreads();
#pragma unroll
      for (int kk = 0; kk < 64; kk += 32) {
        bf16x8 aF[2], bF[4];
#pragma unroll
        for (int mi = 0; mi < 2; ++mi)
          aF[mi] = *(const bf16x8*)&lsA[wm * 32 + mi * 16 + cn][kk + kq];
#pragma unroll
        for (int ni = 0; ni < 4; ++ni)
          bF[ni] = *(const bf16x8*)&lsB[wn * 64 + ni * 16 + cn][kk + kq];
#pragma unroll
        for (int mi = 0; mi < 2; ++mi)
#pragma unroll
          for (int ni = 0; ni < 4; ++ni)
            acc[mi][ni] = __builtin_amdgcn_mfma_f32_16x16x32_bf16(aF[mi], bF[ni], acc[mi][ni], 0, 0, 0);
      }
    }
    // per-sample distance + stats
    const int qw = qBase + wm * 32;
#pragma unroll
    for (int mi = 0; mi < 2; ++mi) {
#pragma unroll
      for (int r = 0; r < 4; ++r) {
        float aq = sqq[s * NQ + qw + mi * 16 + (lane >> 4) * 4 + r];
#pragma unroll
        for (int ni = 0; ni < 4; ++ni) {
          float c = acc[mi][ni][r];
          float dd = sqrtf(fmaxf(aq + sqp_v[ni] - 2.0f * c, 1e-12f));
          sum[mi][ni][r] += dd;
          ssq[mi][ni][r] += dd * dd;
        }
      }
    }
  }
#pragma unroll
  for (int mi = 0; mi < 2; ++mi)
#pragma unroll
    for (int ni = 0; ni < 4; ++ni)
#pragma unroll
      for (int r = 0; r < 4; ++r) {
        int q = qBase + wm * 32 + mi * 16 + (lane >> 4) * 4 + r;
        int p = pBase + wn * 64 + ni * 16 + cn;
        float sm = sum[mi][ni][r];
        float mean = sm * 0.1f;
        float var = (ssq[mi][ni][r] - sm * sm * 0.1f) * (1.0f / 9.0f);
        out[q * NP + p] = mean;
        out[NQ * NP + q * NP + p] = sqrtf(fmaxf(var, 0.0f));
      }
}

// ================= launch =================
extern "C" void kernel_launch(void* const* d_in, const int* in_sizes, int n_in,
                              void* d_out, int out_size, void* d_ws, size_t ws_size,
                              hipStream_t stream) {
  const float* qf   = (const float*)d_in[0];
  const float* pf   = (const float*)d_in[1];
  const float* wmu  = (const float*)d_in[2];
  const float* wrho = (const float*)d_in[3];
  const float* bmu  = (const float*)d_in[4];
  const float* brho = (const float*)d_in[5];
  float* out = (float*)d_out;
  char* ws = (char*)d_ws;
  // workspace layout (52,617,216 B total)
  ushort_t* wt   = (ushort_t*)(ws);              //  5,242,880  W^T bf16 [s][e][k]
  ushort_t* qb   = (ushort_t*)(ws + 5242880);    //  4,194,304  query bf16
  ushort_t* pb   = (ushort_t*)(ws + 9437184);    //  1,048,576  proto bf16
  float*    bvec = (float*)   (ws + 10485760);   //     20,480  bias samples
  float*    sqp  = (float*)   (ws + 10506240);   //      4,096  ||p||^2
  ushort_t* tq   = (ushort_t*)(ws + 10510336);   // 41,943,040  tq bf16 [s][q][e]
  float*    sqq  = (float*)   (ws + 52453376);   //    163,840  ||tq||^2

  // jax.random.key(42) = (0,42); split -> kw, kb  (host-side threefry, constant)
  uint32_t kw0, kw1, kb0, kb1;
#if JAX_PARTITIONABLE
  threefry2x32(0u, 42u, 0u, 0u, &kw0, &kw1);
  threefry2x32(0u, 42u, 0u, 1u, &kb0, &kb1);
#else
  {
    uint32_t a0, a1, c0, c1;
    threefry2x32(0u, 42u, 0u, 2u, &a0, &a1);
    threefry2x32(0u, 42u, 1u, 3u, &c0, &c1);
    kw0 = a0; kw1 = c0; kb0 = a1; kb1 = c1;
  }
#endif

  hipLaunchKernelGGL(gen_w_kernel, dim3(10240), dim3(256), 0, stream, wmu, wrho, wt, kw0, kw1);
  hipLaunchKernelGGL(gen_b_kernel, dim3(20), dim3(256), 0, stream, bmu, brho, bvec, kb0, kb1);
  hipLaunchKernelGGL(cvt_q_kernel, dim3(2048), dim3(256), 0, stream, qf, qb);
  hipLaunchKernelGGL(cvt_p_sqp_kernel, dim3(1024), dim3(64), 0, stream, pf, pb, sqp);
  hipLaunchKernelGGL(gemm_tq_kernel, dim3(64, 8, 10), dim3(256), 0, stream, qb, wt, bvec, tq);
  hipLaunchKernelGGL(sqq_kernel, dim3(NS * NQ), dim3(64), 0, stream, tq, sqq);
  hipLaunchKernelGGL(gemm_dist_kernel, dim3(64, 8), dim3(256), 0, stream, tq, pb, sqq, sqp, out);
}